// Round 12
// baseline (219.612 us; speedup 1.0000x reference)
//
#include <hip/hip_runtime.h>

#define N_NODES  10000
#define N_EDGES  320000
#define D        256
#define N_TASKS  128
#define N_GRAPHS 128

#define CSR_BLOCKS 256
#define EPB (N_EDGES / CSR_BLOCKS)   // 1250 edges per block
#define MM_BX 157                    // (N_NODES+63)/64
#define MM_BLOCKS (MM_BX * 4)        // 628
#define SCAT_BLOCKS ((N_EDGES + 255) / 256)  // 1250

typedef __attribute__((ext_vector_type(8))) _Float16 half8;
typedef __attribute__((ext_vector_type(4))) float floatx4;

__device__ __forceinline__ unsigned short f2h(float f) {
    _Float16 h = (_Float16)f;
    return *(unsigned short*)&h;
}
__device__ __forceinline__ float h2f(unsigned short u) {
    _Float16 h = *(_Float16*)&u;
    return (float)h;
}

// ---------------- prep: histp (blocks 0..255)  ∪  wsplit (blocks 256..447) -----

__global__ __launch_bounds__(256) void prep_kernel(const int* __restrict__ dst,
                                                   unsigned short* __restrict__ histbuf,
                                                   unsigned short* __restrict__ rank,
                                                   const float* __restrict__ W1,
                                                   const float* __restrict__ W2,
                                                   const float* __restrict__ W3,
                                                   unsigned short* __restrict__ wt,
                                                   int* __restrict__ gcount) {
    __shared__ int h[N_NODES];       // 40 KB (histp branch)
    __shared__ float t[32][33];      // (wsplit branch)
    int t0 = threadIdx.x;
    if (blockIdx.x == 0 && t0 == 0) *gcount = 0;   // segment allocator for merge
    if (blockIdx.x < CSR_BLOCKS) {
        int b = blockIdx.x;
        for (int i = t0; i < N_NODES; i += 256) h[i] = 0;
        __syncthreads();
        int e0 = b * EPB;
        for (int i = t0; i < EPB; i += 256) {
            int e = e0 + i;
            int r = atomicAdd(&h[dst[e]], 1);
            rank[e] = (unsigned short)r;
        }
        __syncthreads();
        int* outp = (int*)(histbuf + (size_t)b * N_NODES);   // packed 2 shorts/int
        for (int i = t0; i < N_NODES / 2; i += 256)
            outp[i] = (h[2 * i] & 0xffff) | (h[2 * i + 1] << 16);
    } else {
        int b = blockIdx.x - CSR_BLOCKS;    // 0..191
        int w = b >> 6, tile = b & 63;
        int kt = (tile >> 3) << 5, nt = (tile & 7) << 5;
        const float* W = (w == 0) ? W1 : (w == 1) ? W2 : W3;
        int r = t0 >> 5, c = t0 & 31;
#pragma unroll
        for (int i = 0; i < 4; ++i)
            t[r + 8 * i][c] = W[(size_t)(kt + r + 8 * i) * D + nt + c];
        __syncthreads();
        unsigned short* oh = wt + w * D * D;
#pragma unroll
        for (int i = 0; i < 4; ++i)
            oh[(size_t)(nt + r + 8 * i) * D + kt + c] = f2h(t[c][r + 8 * i]);
    }
}

// ---------------- merge: per-node block-prefixes + atomic segment allocation ----
// 4 threads per node, 64 rows each; LDS combine; rowptr base via atomicAdd
// (per-node internal edge order unchanged -> per-node sums bitwise stable).
__global__ __launch_bounds__(256) void merge_kernel(unsigned short* __restrict__ histbuf,
                                                    int* __restrict__ rowptr,
                                                    int* __restrict__ deg,
                                                    float* __restrict__ isd,
                                                    int* __restrict__ gcount) {
    __shared__ int lds_p[64][4];
    __shared__ int lds_b[64][4];
    int t = threadIdx.x;
    int ng = t >> 2, part = t & 3;
    int node = blockIdx.x * 64 + ng;
    bool valid = node < N_NODES;
    int psum = 0;
    if (valid) {
        const unsigned short* col = histbuf + node;
#pragma unroll 1
        for (int r = 0; r < 64; r += 8) {
            int b = (part << 6) + r;
            int v0 = col[(size_t)(b + 0) * N_NODES];
            int v1 = col[(size_t)(b + 1) * N_NODES];
            int v2 = col[(size_t)(b + 2) * N_NODES];
            int v3 = col[(size_t)(b + 3) * N_NODES];
            int v4 = col[(size_t)(b + 4) * N_NODES];
            int v5 = col[(size_t)(b + 5) * N_NODES];
            int v6 = col[(size_t)(b + 6) * N_NODES];
            int v7 = col[(size_t)(b + 7) * N_NODES];
            psum += v0 + v1 + v2 + v3 + v4 + v5 + v6 + v7;
        }
    }
    lds_p[ng][part] = psum;
    __syncthreads();
    if (valid && part == 0) {
        int p0 = lds_p[ng][0], p1 = lds_p[ng][1], p2 = lds_p[ng][2], p3 = lds_p[ng][3];
        int d = p0 + p1 + p2 + p3;
        rowptr[node] = atomicAdd(gcount, d);
        deg[node] = d;
        isd[node] = rsqrtf((float)(d + 1));   // +1: self-loop
        lds_b[ng][0] = 0; lds_b[ng][1] = p0;
        lds_b[ng][2] = p0 + p1; lds_b[ng][3] = p0 + p1 + p2;
    }
    __syncthreads();
    if (valid) {
        int run = lds_b[ng][part];
        unsigned short* col = histbuf + node;
#pragma unroll 1
        for (int r = 0; r < 64; r += 8) {
            int b = (part << 6) + r;
            int v0 = col[(size_t)(b + 0) * N_NODES];
            int v1 = col[(size_t)(b + 1) * N_NODES];
            int v2 = col[(size_t)(b + 2) * N_NODES];
            int v3 = col[(size_t)(b + 3) * N_NODES];
            int v4 = col[(size_t)(b + 4) * N_NODES];
            int v5 = col[(size_t)(b + 5) * N_NODES];
            int v6 = col[(size_t)(b + 6) * N_NODES];
            int v7 = col[(size_t)(b + 7) * N_NODES];
            col[(size_t)(b + 0) * N_NODES] = (unsigned short)run; run += v0;
            col[(size_t)(b + 1) * N_NODES] = (unsigned short)run; run += v1;
            col[(size_t)(b + 2) * N_NODES] = (unsigned short)run; run += v2;
            col[(size_t)(b + 3) * N_NODES] = (unsigned short)run; run += v3;
            col[(size_t)(b + 4) * N_NODES] = (unsigned short)run; run += v4;
            col[(size_t)(b + 5) * N_NODES] = (unsigned short)run; run += v5;
            col[(size_t)(b + 6) * N_NODES] = (unsigned short)run; run += v6;
            col[(size_t)(b + 7) * N_NODES] = (unsigned short)run; run += v7;
        }
    }
}

// ---------------- mm body (R8-proven BK=32 pipelined loop) ----------------

template <int F32IN>
__device__ __forceinline__ void mm_body(unsigned short (*sA)[40], unsigned short (*sW)[40],
                                        const void* __restrict__ Av,
                                        const unsigned short* __restrict__ Wt,
                                        unsigned short* __restrict__ C,
                                        int row0, int n0, int tid) {
    int lane = tid & 63, wid = tid >> 6;
    int wr = wid >> 1, wc = wid & 1;

    int sr = tid >> 2;              // 0..63 tile row
    int sk = (tid & 3) << 3;        // 0,8,16,24 k elems
    int arow = row0 + sr; if (arow >= N_NODES) arow = N_NODES - 1;  // clamp; stores guarded
    const float*          pAf = (const float*)Av + (size_t)arow * D + sk;
    const unsigned short* pAh = (const unsigned short*)Av + (size_t)arow * D + sk;
    const unsigned short* pW  = Wt + (size_t)(n0 + sr) * D + sk;

    float4 rf0, rf1; uint4 rAh;
    if (F32IN) { rf0 = *(const float4*)pAf; rf1 = *(const float4*)(pAf + 4); }
    else       { rAh = *(const uint4*)pAh; }
    uint4 rW = *(const uint4*)pW;

    int fr = lane & 15;
    int fk = (lane >> 4) << 3;

    floatx4 acc00 = {0.f, 0.f, 0.f, 0.f};
    floatx4 acc01 = acc00, acc10 = acc00, acc11 = acc00;

#pragma unroll 1
    for (int step = 0; step < D / 32; ++step) {
        if (F32IN) {   // in-register f32 -> fp16 convert, then stage
            float vv[8] = {rf0.x, rf0.y, rf0.z, rf0.w, rf1.x, rf1.y, rf1.z, rf1.w};
            union { unsigned short u[8]; uint4 v; } ph;
#pragma unroll
            for (int j = 0; j < 8; ++j) ph.u[j] = f2h(vv[j]);
            *(uint4*)&sA[sr][sk] = ph.v;
        } else {
            *(uint4*)&sA[sr][sk] = rAh;
        }
        *(uint4*)&sW[sr][sk] = rW;
        __syncthreads();
        if (step < D / 32 - 1) {    // prefetch next k-slice
            if (F32IN) {
                rf0 = *(const float4*)(pAf + (step + 1) * 32);
                rf1 = *(const float4*)(pAf + (step + 1) * 32 + 4);
            } else {
                rAh = *(const uint4*)(pAh + (step + 1) * 32);
            }
            rW = *(const uint4*)(pW + (step + 1) * 32);
        }
        half8 a0 = *(const half8*)&sA[(wr << 5) + fr][fk];
        half8 a1 = *(const half8*)&sA[(wr << 5) + 16 + fr][fk];
        half8 b0 = *(const half8*)&sW[(wc << 5) + fr][fk];
        half8 b1 = *(const half8*)&sW[(wc << 5) + 16 + fr][fk];
        acc00 = __builtin_amdgcn_mfma_f32_16x16x32_f16(a0, b0, acc00, 0, 0, 0);
        acc01 = __builtin_amdgcn_mfma_f32_16x16x32_f16(a0, b1, acc01, 0, 0, 0);
        acc10 = __builtin_amdgcn_mfma_f32_16x16x32_f16(a1, b0, acc10, 0, 0, 0);
        acc11 = __builtin_amdgcn_mfma_f32_16x16x32_f16(a1, b1, acc11, 0, 0, 0);
        __syncthreads();
    }

    // C/D layout: col = lane&15, row = (lane>>4)*4 + reg   [m89-verified]
    int crow = (lane >> 4) << 2;
    int colbase = n0 + (wc << 5) + fr;
#pragma unroll
    for (int r = 0; r < 4; ++r) {
        int gr0 = row0 + (wr << 5) + crow + r;
        if (gr0 < N_NODES) {
            C[(size_t)gr0 * D + colbase]      = f2h(acc00[r]);
            C[(size_t)gr0 * D + colbase + 16] = f2h(acc01[r]);
        }
        int gr1 = gr0 + 16;
        if (gr1 < N_NODES) {
            C[(size_t)gr1 * D + colbase]      = f2h(acc10[r]);
            C[(size_t)gr1 * D + colbase + 16] = f2h(acc11[r]);
        }
    }
}

// standalone mm (layers 2,3)
template <int F32IN>
__global__ __launch_bounds__(256) void mm_kernel(const void* __restrict__ Av,
                                                 const unsigned short* __restrict__ Wt,
                                                 unsigned short* __restrict__ C) {
    __shared__ unsigned short sA[64][40], sW[64][40];
    mm_body<F32IN>(sA, sW, Av, Wt, C, blockIdx.x << 6, blockIdx.y << 6, threadIdx.x);
}

// scatter ∪ mm layer-1: blocks [0,628) mm, blocks [628,1878) scatter.
__global__ __launch_bounds__(256) void scatmm_kernel(const float* __restrict__ x,
                                                     const unsigned short* __restrict__ Wt,
                                                     unsigned short* __restrict__ C,
                                                     const int* __restrict__ src,
                                                     const int* __restrict__ dst,
                                                     const unsigned short* __restrict__ rank,
                                                     const int* __restrict__ rowptr,
                                                     const unsigned short* __restrict__ histbuf,
                                                     const float* __restrict__ isd,
                                                     int2* __restrict__ edat) {
    __shared__ unsigned short sA[64][40], sW[64][40];
    if (blockIdx.x < MM_BLOCKS) {
        int row0 = (blockIdx.x % MM_BX) << 6;
        int n0   = (blockIdx.x / MM_BX) << 6;
        mm_body<1>(sA, sW, x, Wt, C, row0, n0, threadIdx.x);
    } else {
        int e = (blockIdx.x - MM_BLOCKS) * 256 + threadIdx.x;
        if (e < N_EDGES) {
            int b = e / EPB;
            int s = src[e], d = dst[e];
            int pos = rowptr[d] + (int)histbuf[(size_t)b * N_NODES + d] + (int)rank[e];
            edat[pos] = make_int2(s, __float_as_int(isd[s] * isd[d]));
        }
    }
}

// ---------------- aggregation: 1 wave/node, 2 rows per dwordx4 load ------------
__device__ __forceinline__ void fma8(uint4 q, float wt, float* acc) {
    acc[0] = fmaf(h2f((unsigned short)(q.x & 0xffff)), wt, acc[0]);
    acc[1] = fmaf(h2f((unsigned short)(q.x >> 16)),    wt, acc[1]);
    acc[2] = fmaf(h2f((unsigned short)(q.y & 0xffff)), wt, acc[2]);
    acc[3] = fmaf(h2f((unsigned short)(q.y >> 16)),    wt, acc[3]);
    acc[4] = fmaf(h2f((unsigned short)(q.z & 0xffff)), wt, acc[4]);
    acc[5] = fmaf(h2f((unsigned short)(q.z >> 16)),    wt, acc[5]);
    acc[6] = fmaf(h2f((unsigned short)(q.w & 0xffff)), wt, acc[6]);
    acc[7] = fmaf(h2f((unsigned short)(q.w >> 16)),    wt, acc[7]);
}

__global__ __launch_bounds__(256, 6) void agg_kernel(const unsigned short* __restrict__ h,
                                                     const int* __restrict__ rowptr,
                                                     const int* __restrict__ degv,
                                                     const int2* __restrict__ edat,
                                                     const float* __restrict__ isd,
                                                     const float* __restrict__ bias,
                                                     unsigned short* __restrict__ outh) {
    int node = (blockIdx.x * blockDim.x + threadIdx.x) >> 6;
    if (node >= N_NODES) return;
    int lane = threadIdx.x & 63;
    int half = lane >> 5;            // 0: even edge of pair, 1: odd edge
    int sub  = lane & 31;            // dims sub*8 .. sub*8+7

    float acc[8] = {0.f, 0.f, 0.f, 0.f, 0.f, 0.f, 0.f, 0.f};

    float isd_i = isd[node];
    float selfw = half ? 0.f : isd_i * isd_i;
    uint4 qs = *(const uint4*)(h + (size_t)node * D + (sub << 3));
    fma8(qs, selfw, acc);

    int e0 = rowptr[node];
    int deg = degv[node];
    for (int base = 0; base < deg; base += 64) {
        int n = deg - base; if (n > 64) n = 64;
        int2 ed = edat[e0 + base + ((lane < n) ? lane : 0)];
        int pairs = (n + 1) >> 1;
        for (int p0 = 0; p0 < pairs; p0 += 8) {
            uint4 q[8]; float wt[8];
#pragma unroll
            for (int u = 0; u < 8; ++u) {
                int idx = ((p0 + u) << 1) + half;
                int idc = (idx < n) ? idx : 0;
                int s = __shfl(ed.x, idc);
                wt[u] = (idx < n && (p0 + u) < pairs)
                            ? __int_as_float(__shfl(ed.y, idc)) : 0.f;
                q[u] = *(const uint4*)(h + (size_t)s * D + (sub << 3));
            }
#pragma unroll
            for (int u = 0; u < 8; ++u) fma8(q[u], wt[u], acc);
        }
    }

#pragma unroll
    for (int i = 0; i < 8; ++i) acc[i] += __shfl_xor(acc[i], 32);

    if (half == 0) {
        const float* bp = bias + (sub << 3);
        float4 b0 = *(const float4*)bp;
        float4 b1 = *(const float4*)(bp + 4);
        float r0 = fmaxf(acc[0] + b0.x, 0.f), r1 = fmaxf(acc[1] + b0.y, 0.f);
        float r2 = fmaxf(acc[2] + b0.z, 0.f), r3 = fmaxf(acc[3] + b0.w, 0.f);
        float r4 = fmaxf(acc[4] + b1.x, 0.f), r5 = fmaxf(acc[5] + b1.y, 0.f);
        float r6 = fmaxf(acc[6] + b1.z, 0.f), r7 = fmaxf(acc[7] + b1.w, 0.f);
        uint4 o;
        o.x = (unsigned)f2h(r0) | ((unsigned)f2h(r1) << 16);
        o.y = (unsigned)f2h(r2) | ((unsigned)f2h(r3) << 16);
        o.z = (unsigned)f2h(r4) | ((unsigned)f2h(r5) << 16);
        o.w = (unsigned)f2h(r6) | ((unsigned)f2h(r7) << 16);
        *(uint4*)(outh + (size_t)node * D + (sub << 3)) = o;
    }
}

// ---------------- fused mean-pool + head (h fp16) ----------------
__global__ __launch_bounds__(256) void poolfinal_kernel(const unsigned short* __restrict__ h,
                                                        const int* __restrict__ batch,
                                                        const float* __restrict__ lw,
                                                        const float* __restrict__ lb,
                                                        float* __restrict__ out) {
    __shared__ float part[4][D];
    __shared__ float p[D];
    int g = blockIdx.x;
    int tid = threadIdx.x, w = tid >> 6, lane = tid & 63;
    int lo = 0, hi = N_NODES;
    while (lo < hi) { int m = (lo + hi) >> 1; if (batch[m] < g) lo = m + 1; else hi = m; }
    int start = lo;
    hi = N_NODES;
    while (lo < hi) { int m = (lo + hi) >> 1; if (batch[m] <= g) lo = m + 1; else hi = m; }
    int end = lo;
    float4 acc = make_float4(0.f, 0.f, 0.f, 0.f);
    for (int nd = start + w; nd < end; nd += 4) {
        ushort4 q = reinterpret_cast<const ushort4*>(h + (size_t)nd * D)[lane];
        acc.x += h2f(q.x); acc.y += h2f(q.y); acc.z += h2f(q.z); acc.w += h2f(q.w);
    }
    reinterpret_cast<float4*>(part[w])[lane] = acc;
    __syncthreads();
    float invc = 1.f / (float)((end > start) ? (end - start) : 1);
    p[tid] = (part[0][tid] + part[1][tid] + part[2][tid] + part[3][tid]) * invc;
    __syncthreads();
    if (tid < N_TASKS) {
        float a = lb[tid];
        for (int k = 0; k < D; ++k) a = fmaf(p[k], lw[k * N_TASKS + tid], a);
        out[g * N_TASKS + tid] = a;
    }
}

extern "C" void kernel_launch(void* const* d_in, const int* in_sizes, int n_in,
                              void* d_out, int out_size, void* d_ws, size_t ws_size,
                              hipStream_t stream) {
    const float* x   = (const float*)d_in[0];
    const int*   ei  = (const int*)d_in[1];
    const int*   bat = (const int*)d_in[2];
    const float* W1  = (const float*)d_in[3];
    const float* b1  = (const float*)d_in[4];
    const float* W2  = (const float*)d_in[5];
    const float* b2  = (const float*)d_in[6];
    const float* W3  = (const float*)d_in[7];
    const float* b3  = (const float*)d_in[8];
    const float* lw  = (const float*)d_in[9];
    const float* lb  = (const float*)d_in[10];
    float* out = (float*)d_out;

    const int* src = ei;
    const int* dst = ei + N_EDGES;

    char* ws = (char*)d_ws;
    unsigned short* gH      = (unsigned short*)(ws + 0);          //  5,120,000 (fp16 agg out)
    unsigned short* hH      = (unsigned short*)(ws + 5120000);    //  5,120,000 (fp16 mm out)
    unsigned short* Wt      = (unsigned short*)(ws + 10240000);   //    393,216
    float*          isd     = (float*)         (ws + 10633216);   //     40,000
    int*            deg     = (int*)           (ws + 10673216);   //     40,000
    int*            rowptr  = (int*)           (ws + 10713216);   //     40,016
    int2*           edat    = (int2*)          (ws + 10753232);   //  2,560,000
    unsigned short* histbuf = (unsigned short*)(ws + 13313232);   //  5,120,000
    unsigned short* rank    = (unsigned short*)(ws + 18433232);   //    640,000
    int*            gcount  = (int*)           (ws + 19073232);   //          4  (~19 MB)

    // 1: histp ∪ wsplit (also zeroes gcount)
    prep_kernel<<<CSR_BLOCKS + 192, 256, 0, stream>>>(dst, histbuf, rank, W1, W2, W3, Wt,
                                                      gcount);
    // 2: per-node prefixes + atomic segment allocation (replaces merge+scan)
    merge_kernel<<<(N_NODES + 63) / 64, 256, 0, stream>>>(histbuf, rowptr, deg, isd, gcount);
    // 3: scatter ∪ mm layer-1
    scatmm_kernel<<<MM_BLOCKS + SCAT_BLOCKS, 256, 0, stream>>>(x, Wt, hH, src, dst, rank,
                                                               rowptr, histbuf, isd, edat);

    dim3 mmgrid(MM_BX, D / 64);                 // 157 x 4
    const int AGG_BLOCKS = N_NODES / 4;         // 2500 (1 wave per node)

    // 4..8
    agg_kernel<<<AGG_BLOCKS, 256, 0, stream>>>(hH, rowptr, deg, edat, isd, b1, gH);
    mm_kernel<0><<<mmgrid, 256, 0, stream>>>(gH, Wt + D * D, hH);
    agg_kernel<<<AGG_BLOCKS, 256, 0, stream>>>(hH, rowptr, deg, edat, isd, b2, gH);
    mm_kernel<0><<<mmgrid, 256, 0, stream>>>(gH, Wt + 2 * D * D, hH);
    agg_kernel<<<AGG_BLOCKS, 256, 0, stream>>>(hH, rowptr, deg, edat, isd, b3, gH);
    poolfinal_kernel<<<N_GRAPHS, 256, 0, stream>>>(gH, bat, lw, lb, out);
}

// Round 13
// 128.662 us; speedup vs baseline: 1.7069x; 1.7069x over previous
//
#include <hip/hip_runtime.h>

#define N_NODES  10000
#define N_EDGES  320000
#define D        256
#define N_TASKS  128
#define N_GRAPHS 128

#define CSR_BLOCKS 256
#define EPB (N_EDGES / CSR_BLOCKS)   // 1250 edges per block
#define MM_BX 157                    // (N_NODES+63)/64
#define MM_BLOCKS (MM_BX * 4)        // 628
#define SCAT_BLOCKS ((N_EDGES + 255) / 256)  // 1250

typedef __attribute__((ext_vector_type(8))) _Float16 half8;
typedef __attribute__((ext_vector_type(4))) float floatx4;

__device__ __forceinline__ unsigned short f2h(float f) {
    _Float16 h = (_Float16)f;
    return *(unsigned short*)&h;
}
__device__ __forceinline__ float h2f(unsigned short u) {
    _Float16 h = *(_Float16*)&u;
    return (float)h;
}

// ---------------- prep: histp (blocks 0..255)  ∪  wsplit (blocks 256..447) -----

__global__ __launch_bounds__(256) void prep_kernel(const int* __restrict__ dst,
                                                   unsigned short* __restrict__ histbuf,
                                                   unsigned short* __restrict__ rank,
                                                   const float* __restrict__ W1,
                                                   const float* __restrict__ W2,
                                                   const float* __restrict__ W3,
                                                   unsigned short* __restrict__ wt,
                                                   int* __restrict__ gcount) {
    __shared__ int h[N_NODES];       // 40 KB (histp branch)
    __shared__ float t[32][33];      // (wsplit branch)
    int t0 = threadIdx.x;
    if (blockIdx.x == 0 && t0 == 0) *gcount = 0;   // segment allocator for merge
    if (blockIdx.x < CSR_BLOCKS) {
        int b = blockIdx.x;
        for (int i = t0; i < N_NODES; i += 256) h[i] = 0;
        __syncthreads();
        int e0 = b * EPB;
        for (int i = t0; i < EPB; i += 256) {
            int e = e0 + i;
            int r = atomicAdd(&h[dst[e]], 1);
            rank[e] = (unsigned short)r;
        }
        __syncthreads();
        int* outp = (int*)(histbuf + (size_t)b * N_NODES);   // packed 2 shorts/int
        for (int i = t0; i < N_NODES / 2; i += 256)
            outp[i] = (h[2 * i] & 0xffff) | (h[2 * i + 1] << 16);
    } else {
        int b = blockIdx.x - CSR_BLOCKS;    // 0..191
        int w = b >> 6, tile = b & 63;
        int kt = (tile >> 3) << 5, nt = (tile & 7) << 5;
        const float* W = (w == 0) ? W1 : (w == 1) ? W2 : W3;
        int r = t0 >> 5, c = t0 & 31;
#pragma unroll
        for (int i = 0; i < 4; ++i)
            t[r + 8 * i][c] = W[(size_t)(kt + r + 8 * i) * D + nt + c];
        __syncthreads();
        unsigned short* oh = wt + w * D * D;
#pragma unroll
        for (int i = 0; i < 4; ++i)
            oh[(size_t)(nt + r + 8 * i) * D + kt + c] = f2h(t[c][r + 8 * i]);
    }
}

// ---------------- merge: per-node block-prefixes + atomic segment allocation ----
// 4 threads per node, 64 rows each; LDS combine; rowptr base via atomicAdd
// (per-node internal edge order unchanged -> per-node sums bitwise stable).
__global__ __launch_bounds__(256) void merge_kernel(unsigned short* __restrict__ histbuf,
                                                    int* __restrict__ rowptr,
                                                    int* __restrict__ deg,
                                                    float* __restrict__ isd,
                                                    int* __restrict__ gcount) {
    __shared__ int lds_p[64][4];
    __shared__ int lds_b[64][4];
    int t = threadIdx.x;
    int ng = t >> 2, part = t & 3;
    int node = blockIdx.x * 64 + ng;
    bool valid = node < N_NODES;
    int psum = 0;
    if (valid) {
        const unsigned short* col = histbuf + node;
#pragma unroll 1
        for (int r = 0; r < 64; r += 8) {
            int b = (part << 6) + r;
            int v0 = col[(size_t)(b + 0) * N_NODES];
            int v1 = col[(size_t)(b + 1) * N_NODES];
            int v2 = col[(size_t)(b + 2) * N_NODES];
            int v3 = col[(size_t)(b + 3) * N_NODES];
            int v4 = col[(size_t)(b + 4) * N_NODES];
            int v5 = col[(size_t)(b + 5) * N_NODES];
            int v6 = col[(size_t)(b + 6) * N_NODES];
            int v7 = col[(size_t)(b + 7) * N_NODES];
            psum += v0 + v1 + v2 + v3 + v4 + v5 + v6 + v7;
        }
    }
    lds_p[ng][part] = psum;
    __syncthreads();
    if (valid && part == 0) {
        int p0 = lds_p[ng][0], p1 = lds_p[ng][1], p2 = lds_p[ng][2], p3 = lds_p[ng][3];
        int d = p0 + p1 + p2 + p3;
        rowptr[node] = atomicAdd(gcount, d);
        deg[node] = d;
        isd[node] = rsqrtf((float)(d + 1));   // +1: self-loop
        lds_b[ng][0] = 0; lds_b[ng][1] = p0;
        lds_b[ng][2] = p0 + p1; lds_b[ng][3] = p0 + p1 + p2;
    }
    __syncthreads();
    if (valid) {
        int run = lds_b[ng][part];
        unsigned short* col = histbuf + node;
#pragma unroll 1
        for (int r = 0; r < 64; r += 8) {
            int b = (part << 6) + r;
            int v0 = col[(size_t)(b + 0) * N_NODES];
            int v1 = col[(size_t)(b + 1) * N_NODES];
            int v2 = col[(size_t)(b + 2) * N_NODES];
            int v3 = col[(size_t)(b + 3) * N_NODES];
            int v4 = col[(size_t)(b + 4) * N_NODES];
            int v5 = col[(size_t)(b + 5) * N_NODES];
            int v6 = col[(size_t)(b + 6) * N_NODES];
            int v7 = col[(size_t)(b + 7) * N_NODES];
            col[(size_t)(b + 0) * N_NODES] = (unsigned short)run; run += v0;
            col[(size_t)(b + 1) * N_NODES] = (unsigned short)run; run += v1;
            col[(size_t)(b + 2) * N_NODES] = (unsigned short)run; run += v2;
            col[(size_t)(b + 3) * N_NODES] = (unsigned short)run; run += v3;
            col[(size_t)(b + 4) * N_NODES] = (unsigned short)run; run += v4;
            col[(size_t)(b + 5) * N_NODES] = (unsigned short)run; run += v5;
            col[(size_t)(b + 6) * N_NODES] = (unsigned short)run; run += v6;
            col[(size_t)(b + 7) * N_NODES] = (unsigned short)run; run += v7;
        }
    }
}

// ---------------- mm body (R8-proven BK=32 pipelined loop) ----------------

template <int F32IN>
__device__ __forceinline__ void mm_body(unsigned short (*sA)[40], unsigned short (*sW)[40],
                                        const void* __restrict__ Av,
                                        const unsigned short* __restrict__ Wt,
                                        unsigned short* __restrict__ C,
                                        int row0, int n0, int tid) {
    int lane = tid & 63, wid = tid >> 6;
    int wr = wid >> 1, wc = wid & 1;

    int sr = tid >> 2;              // 0..63 tile row
    int sk = (tid & 3) << 3;        // 0,8,16,24 k elems
    int arow = row0 + sr; if (arow >= N_NODES) arow = N_NODES - 1;  // clamp; stores guarded
    const float*          pAf = (const float*)Av + (size_t)arow * D + sk;
    const unsigned short* pAh = (const unsigned short*)Av + (size_t)arow * D + sk;
    const unsigned short* pW  = Wt + (size_t)(n0 + sr) * D + sk;

    float4 rf0, rf1; uint4 rAh;
    if (F32IN) { rf0 = *(const float4*)pAf; rf1 = *(const float4*)(pAf + 4); }
    else       { rAh = *(const uint4*)pAh; }
    uint4 rW = *(const uint4*)pW;

    int fr = lane & 15;
    int fk = (lane >> 4) << 3;

    floatx4 acc00 = {0.f, 0.f, 0.f, 0.f};
    floatx4 acc01 = acc00, acc10 = acc00, acc11 = acc00;

#pragma unroll 1
    for (int step = 0; step < D / 32; ++step) {
        if (F32IN) {   // in-register f32 -> fp16 convert, then stage
            float vv[8] = {rf0.x, rf0.y, rf0.z, rf0.w, rf1.x, rf1.y, rf1.z, rf1.w};
            union { unsigned short u[8]; uint4 v; } ph;
#pragma unroll
            for (int j = 0; j < 8; ++j) ph.u[j] = f2h(vv[j]);
            *(uint4*)&sA[sr][sk] = ph.v;
        } else {
            *(uint4*)&sA[sr][sk] = rAh;
        }
        *(uint4*)&sW[sr][sk] = rW;
        __syncthreads();
        if (step < D / 32 - 1) {    // prefetch next k-slice
            if (F32IN) {
                rf0 = *(const float4*)(pAf + (step + 1) * 32);
                rf1 = *(const float4*)(pAf + (step + 1) * 32 + 4);
            } else {
                rAh = *(const uint4*)(pAh + (step + 1) * 32);
            }
            rW = *(const uint4*)(pW + (step + 1) * 32);
        }
        half8 a0 = *(const half8*)&sA[(wr << 5) + fr][fk];
        half8 a1 = *(const half8*)&sA[(wr << 5) + 16 + fr][fk];
        half8 b0 = *(const half8*)&sW[(wc << 5) + fr][fk];
        half8 b1 = *(const half8*)&sW[(wc << 5) + 16 + fr][fk];
        acc00 = __builtin_amdgcn_mfma_f32_16x16x32_f16(a0, b0, acc00, 0, 0, 0);
        acc01 = __builtin_amdgcn_mfma_f32_16x16x32_f16(a0, b1, acc01, 0, 0, 0);
        acc10 = __builtin_amdgcn_mfma_f32_16x16x32_f16(a1, b0, acc10, 0, 0, 0);
        acc11 = __builtin_amdgcn_mfma_f32_16x16x32_f16(a1, b1, acc11, 0, 0, 0);
        __syncthreads();
    }

    // C/D layout: col = lane&15, row = (lane>>4)*4 + reg   [m89-verified]
    int crow = (lane >> 4) << 2;
    int colbase = n0 + (wc << 5) + fr;
#pragma unroll
    for (int r = 0; r < 4; ++r) {
        int gr0 = row0 + (wr << 5) + crow + r;
        if (gr0 < N_NODES) {
            C[(size_t)gr0 * D + colbase]      = f2h(acc00[r]);
            C[(size_t)gr0 * D + colbase + 16] = f2h(acc01[r]);
        }
        int gr1 = gr0 + 16;
        if (gr1 < N_NODES) {
            C[(size_t)gr1 * D + colbase]      = f2h(acc10[r]);
            C[(size_t)gr1 * D + colbase + 16] = f2h(acc11[r]);
        }
    }
}

// standalone mm (layers 2,3)
template <int F32IN>
__global__ __launch_bounds__(256) void mm_kernel(const void* __restrict__ Av,
                                                 const unsigned short* __restrict__ Wt,
                                                 unsigned short* __restrict__ C) {
    __shared__ unsigned short sA[64][40], sW[64][40];
    mm_body<F32IN>(sA, sW, Av, Wt, C, blockIdx.x << 6, blockIdx.y << 6, threadIdx.x);
}

// scatter ∪ mm layer-1: blocks [0,628) mm, blocks [628,1878) scatter.
__global__ __launch_bounds__(256) void scatmm_kernel(const float* __restrict__ x,
                                                     const unsigned short* __restrict__ Wt,
                                                     unsigned short* __restrict__ C,
                                                     const int* __restrict__ src,
                                                     const int* __restrict__ dst,
                                                     const unsigned short* __restrict__ rank,
                                                     const int* __restrict__ rowptr,
                                                     const unsigned short* __restrict__ histbuf,
                                                     const float* __restrict__ isd,
                                                     int2* __restrict__ edat) {
    __shared__ unsigned short sA[64][40], sW[64][40];
    if (blockIdx.x < MM_BLOCKS) {
        int row0 = (blockIdx.x % MM_BX) << 6;
        int n0   = (blockIdx.x / MM_BX) << 6;
        mm_body<1>(sA, sW, x, Wt, C, row0, n0, threadIdx.x);
    } else {
        int e = (blockIdx.x - MM_BLOCKS) * 256 + threadIdx.x;
        if (e < N_EDGES) {
            int b = e / EPB;
            int s = src[e], d = dst[e];
            int pos = rowptr[d] + (int)histbuf[(size_t)b * N_NODES + d] + (int)rank[e];
            edat[pos] = make_int2(s, __float_as_int(isd[s] * isd[d]));
        }
    }
}

// ---------------- aggregation: 1 wave/node, 2 rows per dwordx4 load ------------
__device__ __forceinline__ void fma8(uint4 q, float wt, float* acc) {
    acc[0] = fmaf(h2f((unsigned short)(q.x & 0xffff)), wt, acc[0]);
    acc[1] = fmaf(h2f((unsigned short)(q.x >> 16)),    wt, acc[1]);
    acc[2] = fmaf(h2f((unsigned short)(q.y & 0xffff)), wt, acc[2]);
    acc[3] = fmaf(h2f((unsigned short)(q.y >> 16)),    wt, acc[3]);
    acc[4] = fmaf(h2f((unsigned short)(q.z & 0xffff)), wt, acc[4]);
    acc[5] = fmaf(h2f((unsigned short)(q.z >> 16)),    wt, acc[5]);
    acc[6] = fmaf(h2f((unsigned short)(q.w & 0xffff)), wt, acc[6]);
    acc[7] = fmaf(h2f((unsigned short)(q.w >> 16)),    wt, acc[7]);
}

__global__ __launch_bounds__(256) void agg_kernel(const unsigned short* __restrict__ h,
                                                  const int* __restrict__ rowptr,
                                                  const int* __restrict__ degv,
                                                  const int2* __restrict__ edat,
                                                  const float* __restrict__ isd,
                                                  const float* __restrict__ bias,
                                                  unsigned short* __restrict__ outh) {
    int node = (blockIdx.x * blockDim.x + threadIdx.x) >> 6;
    if (node >= N_NODES) return;
    int lane = threadIdx.x & 63;
    int half = lane >> 5;            // 0: even edge of pair, 1: odd edge
    int sub  = lane & 31;            // dims sub*8 .. sub*8+7

    float acc[8] = {0.f, 0.f, 0.f, 0.f, 0.f, 0.f, 0.f, 0.f};

    float isd_i = isd[node];
    float selfw = half ? 0.f : isd_i * isd_i;
    uint4 qs = *(const uint4*)(h + (size_t)node * D + (sub << 3));
    fma8(qs, selfw, acc);

    int e0 = rowptr[node];
    int deg = degv[node];
    for (int base = 0; base < deg; base += 64) {
        int n = deg - base; if (n > 64) n = 64;
        int2 ed = edat[e0 + base + ((lane < n) ? lane : 0)];
        int pairs = (n + 1) >> 1;
        for (int p0 = 0; p0 < pairs; p0 += 8) {
            uint4 q[8]; float wt[8];
#pragma unroll
            for (int u = 0; u < 8; ++u) {
                int idx = ((p0 + u) << 1) + half;
                int idc = (idx < n) ? idx : 0;
                int s = __shfl(ed.x, idc);
                wt[u] = (idx < n && (p0 + u) < pairs)
                            ? __int_as_float(__shfl(ed.y, idc)) : 0.f;
                q[u] = *(const uint4*)(h + (size_t)s * D + (sub << 3));
            }
#pragma unroll
            for (int u = 0; u < 8; ++u) fma8(q[u], wt[u], acc);
        }
    }

#pragma unroll
    for (int i = 0; i < 8; ++i) acc[i] += __shfl_xor(acc[i], 32);

    if (half == 0) {
        const float* bp = bias + (sub << 3);
        float4 b0 = *(const float4*)bp;
        float4 b1 = *(const float4*)(bp + 4);
        float r0 = fmaxf(acc[0] + b0.x, 0.f), r1 = fmaxf(acc[1] + b0.y, 0.f);
        float r2 = fmaxf(acc[2] + b0.z, 0.f), r3 = fmaxf(acc[3] + b0.w, 0.f);
        float r4 = fmaxf(acc[4] + b1.x, 0.f), r5 = fmaxf(acc[5] + b1.y, 0.f);
        float r6 = fmaxf(acc[6] + b1.z, 0.f), r7 = fmaxf(acc[7] + b1.w, 0.f);
        uint4 o;
        o.x = (unsigned)f2h(r0) | ((unsigned)f2h(r1) << 16);
        o.y = (unsigned)f2h(r2) | ((unsigned)f2h(r3) << 16);
        o.z = (unsigned)f2h(r4) | ((unsigned)f2h(r5) << 16);
        o.w = (unsigned)f2h(r6) | ((unsigned)f2h(r7) << 16);
        *(uint4*)(outh + (size_t)node * D + (sub << 3)) = o;
    }
}

// ---------------- fused mean-pool + head (h fp16) ----------------
__global__ __launch_bounds__(256) void poolfinal_kernel(const unsigned short* __restrict__ h,
                                                        const int* __restrict__ batch,
                                                        const float* __restrict__ lw,
                                                        const float* __restrict__ lb,
                                                        float* __restrict__ out) {
    __shared__ float part[4][D];
    __shared__ float p[D];
    int g = blockIdx.x;
    int tid = threadIdx.x, w = tid >> 6, lane = tid & 63;
    int lo = 0, hi = N_NODES;
    while (lo < hi) { int m = (lo + hi) >> 1; if (batch[m] < g) lo = m + 1; else hi = m; }
    int start = lo;
    hi = N_NODES;
    while (lo < hi) { int m = (lo + hi) >> 1; if (batch[m] <= g) lo = m + 1; else hi = m; }
    int end = lo;
    float4 acc = make_float4(0.f, 0.f, 0.f, 0.f);
    for (int nd = start + w; nd < end; nd += 4) {
        ushort4 q = reinterpret_cast<const ushort4*>(h + (size_t)nd * D)[lane];
        acc.x += h2f(q.x); acc.y += h2f(q.y); acc.z += h2f(q.z); acc.w += h2f(q.w);
    }
    reinterpret_cast<float4*>(part[w])[lane] = acc;
    __syncthreads();
    float invc = 1.f / (float)((end > start) ? (end - start) : 1);
    p[tid] = (part[0][tid] + part[1][tid] + part[2][tid] + part[3][tid]) * invc;
    __syncthreads();
    if (tid < N_TASKS) {
        float a = lb[tid];
        for (int k = 0; k < D; ++k) a = fmaf(p[k], lw[k * N_TASKS + tid], a);
        out[g * N_TASKS + tid] = a;
    }
}

extern "C" void kernel_launch(void* const* d_in, const int* in_sizes, int n_in,
                              void* d_out, int out_size, void* d_ws, size_t ws_size,
                              hipStream_t stream) {
    const float* x   = (const float*)d_in[0];
    const int*   ei  = (const int*)d_in[1];
    const int*   bat = (const int*)d_in[2];
    const float* W1  = (const float*)d_in[3];
    const float* b1  = (const float*)d_in[4];
    const float* W2  = (const float*)d_in[5];
    const float* b2  = (const float*)d_in[6];
    const float* W3  = (const float*)d_in[7];
    const float* b3  = (const float*)d_in[8];
    const float* lw  = (const float*)d_in[9];
    const float* lb  = (const float*)d_in[10];
    float* out = (float*)d_out;

    const int* src = ei;
    const int* dst = ei + N_EDGES;

    char* ws = (char*)d_ws;
    unsigned short* gH      = (unsigned short*)(ws + 0);          //  5,120,000 (fp16 agg out)
    unsigned short* hH      = (unsigned short*)(ws + 5120000);    //  5,120,000 (fp16 mm out)
    unsigned short* Wt      = (unsigned short*)(ws + 10240000);   //    393,216
    float*          isd     = (float*)         (ws + 10633216);   //     40,000
    int*            deg     = (int*)           (ws + 10673216);   //     40,000
    int*            rowptr  = (int*)           (ws + 10713216);   //     40,016
    int2*           edat    = (int2*)          (ws + 10753232);   //  2,560,000
    unsigned short* histbuf = (unsigned short*)(ws + 13313232);   //  5,120,000
    unsigned short* rank    = (unsigned short*)(ws + 18433232);   //    640,000
    int*            gcount  = (int*)           (ws + 19073232);   //          4  (~19 MB)

    // 1: histp ∪ wsplit (also zeroes gcount)
    prep_kernel<<<CSR_BLOCKS + 192, 256, 0, stream>>>(dst, histbuf, rank, W1, W2, W3, Wt,
                                                      gcount);
    // 2: per-node prefixes + atomic segment allocation (replaces merge+scan)
    merge_kernel<<<(N_NODES + 63) / 64, 256, 0, stream>>>(histbuf, rowptr, deg, isd, gcount);
    // 3: scatter ∪ mm layer-1
    scatmm_kernel<<<MM_BLOCKS + SCAT_BLOCKS, 256, 0, stream>>>(x, Wt, hH, src, dst, rank,
                                                               rowptr, histbuf, isd, edat);

    dim3 mmgrid(MM_BX, D / 64);                 // 157 x 4
    const int AGG_BLOCKS = N_NODES / 4;         // 2500 (1 wave per node)

    // 4..8
    agg_kernel<<<AGG_BLOCKS, 256, 0, stream>>>(hH, rowptr, deg, edat, isd, b1, gH);
    mm_kernel<0><<<mmgrid, 256, 0, stream>>>(gH, Wt + D * D, hH);
    agg_kernel<<<AGG_BLOCKS, 256, 0, stream>>>(hH, rowptr, deg, edat, isd, b2, gH);
    mm_kernel<0><<<mmgrid, 256, 0, stream>>>(gH, Wt + 2 * D * D, hH);
    agg_kernel<<<AGG_BLOCKS, 256, 0, stream>>>(hH, rowptr, deg, edat, isd, b3, gH);
    poolfinal_kernel<<<N_GRAPHS, 256, 0, stream>>>(gH, bat, lw, lb, out);
}